// Round 6
// baseline (8061.575 us; speedup 1.0000x reference)
//
#include <hip/hip_runtime.h>

#define NDIM 2048
#define KDIM 4096
#define NN (NDIM * NDIM)

// ==================== register-array micro-solvers (fully unrolled: all
// register indices static — rule: dynamic index => scratch spill) =========
__device__ __forceinline__ void row_triu_solve(float x[64], const float* __restrict__ U,
                                               const float* __restrict__ rd) {
#pragma unroll
  for (int c = 0; c < 64; ++c) {
    float s = x[c];
#pragma unroll
    for (int p = 0; p < c; ++p) s -= x[p] * U[p * 65 + c];
    x[c] = s * rd[c];
  }
}
__device__ __forceinline__ void row_dense_sub(float x1[64], const float x0[64],
                                              const float* __restrict__ D) {
#pragma unroll
  for (int c = 0; c < 64; ++c) {
    float s = x1[c];
#pragma unroll
    for (int p = 0; p < 64; ++p) s -= x0[p] * D[p * 65 + c];
    x1[c] = s;
  }
}
__device__ __forceinline__ void col_unitL_solve(float y[64], const float* __restrict__ Lb) {
#pragma unroll
  for (int j = 1; j < 64; ++j) {
    float s = y[j];
#pragma unroll
    for (int i = 0; i < j; ++i) s -= Lb[j * 65 + i] * y[i];
    y[j] = s;
  }
}
__device__ __forceinline__ void col_dense_sub(float y1[64], const float y0[64],
                                              const float* __restrict__ D) {
#pragma unroll
  for (int j = 0; j < 64; ++j) {
    float s = y1[j];
#pragma unroll
    for (int i = 0; i < 64; ++i) s -= D[j * 65 + i] * y0[i];
    y1[j] = s;
  }
}
__device__ __forceinline__ void col_triu_bwd_solve(float y[64], const float* __restrict__ U,
                                                   const float* __restrict__ rd) {
#pragma unroll
  for (int j = 63; j >= 0; --j) {
    float s = y[j];
#pragma unroll
    for (int i = j + 1; i < 64; ++i) s -= U[j * 65 + i] * y[i];
    y[j] = s * rd[j];
  }
}

// load a 64x64 block of E (row-major, ld=NDIM) into LDS with stride 65
__device__ __forceinline__ void load64(float* __restrict__ Dst, const float* __restrict__ src,
                                       int t, int nthr) {
  for (int idx = t; idx < 4096; idx += nthr)
    Dst[(idx >> 6) * 65 + (idx & 63)] = src[(size_t)(idx >> 6) * NDIM + (idx & 63)];
}

// in-LDS LU (no pivot) of a 128x128 tile, stride 129. 512 threads.
__device__ __forceinline__ void lu128_inlds(float* __restrict__ S, int t) {
  const int row = t & 127, cw = t >> 7;  // 4 column workers per row
  for (int j = 0; j < 127; ++j) {
    const float rp = 1.0f / S[j * 129 + j];
    if (cw == 0 && row > j) S[row * 129 + j] *= rp;
    __syncthreads();
    if (row > j) {
      const float lv = S[row * 129 + j];
      for (int c = j + 1 + cw; c < 128; c += 4) S[row * 129 + c] -= lv * S[j * 129 + c];
    }
    __syncthreads();
  }
}

// ==================== big NT GEMM: C[2048][2048] = A(2048x4096)*B(2048x4096)^T
// 128x128 tile, BK=16, 512 threads (8 waves/CU), 8x4 per thread, dbuf LDS.
__global__ __launch_bounds__(512) void gemm_nt_big(const float* __restrict__ A,
                                                   const float* __restrict__ B,
                                                   float* __restrict__ C) {
  __shared__ float As[2][16][128];
  __shared__ float Bs[2][16][128];
  const int t = threadIdx.x;
  const int tx = t & 31;       // col group (4 cols)
  const int ty = t >> 5;       // row group (8 rows)
  const int lr = t >> 2;       // 0..127 row to load
  const int lk = (t & 3) * 4;  // k offset
  const float* Ap = A + (size_t)(blockIdx.y * 128 + lr) * KDIM + lk;
  const float* Bp = B + (size_t)(blockIdx.x * 128 + lr) * KDIM + lk;
  float acc[8][4];
#pragma unroll
  for (int r = 0; r < 8; ++r)
#pragma unroll
    for (int c = 0; c < 4; ++c) acc[r][c] = 0.f;
  {
    float4 a = *(const float4*)Ap;
    float4 b = *(const float4*)Bp;
    As[0][lk + 0][lr] = a.x; As[0][lk + 1][lr] = a.y;
    As[0][lk + 2][lr] = a.z; As[0][lk + 3][lr] = a.w;
    Bs[0][lk + 0][lr] = b.x; Bs[0][lk + 1][lr] = b.y;
    Bs[0][lk + 2][lr] = b.z; Bs[0][lk + 3][lr] = b.w;
  }
  int cur = 0;
  for (int k0 = 16;; k0 += 16) {
    const bool more = k0 < KDIM;
    float4 na, nb;
    if (more) {
      na = *(const float4*)(Ap + k0);
      nb = *(const float4*)(Bp + k0);
    }
    __syncthreads();
#pragma unroll
    for (int kk = 0; kk < 16; ++kk) {
      float ra[8], rb[4];
#pragma unroll
      for (int r = 0; r < 8; ++r) ra[r] = As[cur][kk][ty * 8 + r];
#pragma unroll
      for (int c = 0; c < 4; ++c) rb[c] = Bs[cur][kk][tx * 4 + c];
#pragma unroll
      for (int r = 0; r < 8; ++r)
#pragma unroll
        for (int c = 0; c < 4; ++c) acc[r][c] += ra[r] * rb[c];
    }
    if (!more) break;
    const int nx = cur ^ 1;
    As[nx][lk + 0][lr] = na.x; As[nx][lk + 1][lr] = na.y;
    As[nx][lk + 2][lr] = na.z; As[nx][lk + 3][lr] = na.w;
    Bs[nx][lk + 0][lr] = nb.x; Bs[nx][lk + 1][lr] = nb.y;
    Bs[nx][lk + 2][lr] = nb.z; Bs[nx][lk + 3][lr] = nb.w;
    cur = nx;
  }
#pragma unroll
  for (int r = 0; r < 8; ++r) {
    float* p = C + (size_t)(blockIdx.y * 128 + ty * 8 + r) * NDIM + blockIdx.x * 128 + tx * 4;
    float4 v = {acc[r][0], acc[r][1], acc[r][2], acc[r][3]};
    *(float4*)p = v;
  }
}

// ==================== generic 64x64 tile GEMM (finals) ====================
template <bool TA>
__global__ __launch_bounds__(256) void gemm_tile64(const float* __restrict__ A,
                                                   const float* __restrict__ B,
                                                   float* C, int M, int N, int K,
                                                   int lda, int ldb, int ldc,
                                                   float alpha, float beta) {
  __shared__ float As[16][64];
  __shared__ float Bs[16][64];
  const int t = threadIdx.x;
  const int tx = t & 15, ty = t >> 4;
  const int i0 = blockIdx.y * 64, j0 = blockIdx.x * 64;
  float acc[4][4];
#pragma unroll
  for (int r = 0; r < 4; ++r)
#pragma unroll
    for (int c = 0; c < 4; ++c) acc[r][c] = 0.f;

  for (int k0 = 0; k0 < K; k0 += 16) {
    float4 av, bv;
    if (TA) {
      av = *(const float4*)(A + (size_t)(k0 + ty) * lda + i0 + tx * 4);
    } else {
      av = *(const float4*)(A + (size_t)(i0 + (t >> 2)) * lda + k0 + (t & 3) * 4);
    }
    bv = *(const float4*)(B + (size_t)(k0 + ty) * ldb + j0 + tx * 4);
    __syncthreads();
    if (TA) {
      *(float4*)&As[ty][tx * 4] = av;
    } else {
      const int i = t >> 2, k4 = (t & 3) * 4;
      As[k4 + 0][i] = av.x; As[k4 + 1][i] = av.y;
      As[k4 + 2][i] = av.z; As[k4 + 3][i] = av.w;
    }
    *(float4*)&Bs[ty][tx * 4] = bv;
    __syncthreads();
#pragma unroll
    for (int kk = 0; kk < 16; ++kk) {
      float ra[4], rb[4];
#pragma unroll
      for (int r = 0; r < 4; ++r) ra[r] = As[kk][ty * 4 + r];
#pragma unroll
      for (int c = 0; c < 4; ++c) rb[c] = Bs[kk][tx * 4 + c];
#pragma unroll
      for (int r = 0; r < 4; ++r)
#pragma unroll
        for (int c = 0; c < 4; ++c) acc[r][c] += ra[r] * rb[c];
    }
  }
#pragma unroll
  for (int r = 0; r < 4; ++r) {
    float* p = C + (size_t)(i0 + ty * 4 + r) * ldc + j0 + tx * 4;
    float4 old = *(const float4*)p;
    float4 v;
    v.x = alpha * acc[r][0] + beta * old.x;
    v.y = alpha * acc[r][1] + beta * old.y;
    v.z = alpha * acc[r][2] + beta * old.z;
    v.w = alpha * acc[r][3] + beta * old.w;
    *(float4*)p = v;
  }
}

// ==================== E = 0.5*(E + P) + 0.5*(R - R^T) =====================
__global__ __launch_bounds__(256) void make_E(float* E, const float* __restrict__ P,
                                              const float* __restrict__ R) {
  __shared__ float Rt[64][65];
  const int bi = blockIdx.y, bj = blockIdx.x;
  const int t = threadIdx.x;
  for (int idx = t; idx < 4096; idx += 256) {
    int r = idx >> 6, c = idx & 63;
    Rt[r][c] = R[(size_t)(bj * 64 + r) * NDIM + bi * 64 + c];
  }
  __syncthreads();
  for (int idx = t; idx < 4096; idx += 256) {
    int r = idx >> 6, c = idx & 63;
    size_t off = (size_t)(bi * 64 + r) * NDIM + bj * 64 + c;
    E[off] = 0.5f * (E[off] + P[off]) + 0.5f * (R[off] - Rt[c][r]);
  }
}

// ==================== LU NB=128 ===========================================
__global__ __launch_bounds__(512) void lu_diag128(float* __restrict__ E, int k) {
  __shared__ float S[128 * 129];
  const int t = threadIdx.x;
  for (int idx = t; idx < 16384; idx += 512)
    S[(idx >> 7) * 129 + (idx & 127)] = E[(size_t)(k + (idx >> 7)) * NDIM + k + (idx & 127)];
  __syncthreads();
  lu128_inlds(S, t);
  for (int idx = t; idx < 16384; idx += 512)
    E[(size_t)(k + (idx >> 7)) * NDIM + k + (idx & 127)] = S[(idx >> 7) * 129 + (idx & 127)];
}

// panels: blocks [0,nbrow): rows below (L21 = A21*U11^-1, two-stage);
//         blocks [nbrow,2nbrow): cols right (U12 = L11^-1*A12, two-stage).
__global__ __launch_bounds__(256) void lu_panels128(float* __restrict__ E, int k, int nbrow) {
  __shared__ float D0[64 * 65], D1[64 * 65], D2[64 * 65];
  __shared__ float rd0[64], rd2[64];
  const int t = threadIdx.x;
  const bool rowside = (int)blockIdx.x < nbrow;
  load64(D0, E + (size_t)k * NDIM + k, t, 256);
  if (rowside)
    load64(D1, E + (size_t)k * NDIM + k + 64, t, 256);        // U01
  else
    load64(D1, E + (size_t)(k + 64) * NDIM + k, t, 256);      // L10
  load64(D2, E + (size_t)(k + 64) * NDIM + k + 64, t, 256);
  __syncthreads();
  if (t < 64) { rd0[t] = 1.0f / D0[t * 65 + t]; rd2[t] = 1.0f / D2[t * 65 + t]; }
  __syncthreads();
  if (rowside) {
    const int row = k + 128 + (int)blockIdx.x * 256 + t;
    if (row >= NDIM) return;
    float* pr = E + (size_t)row * NDIM + k;
    float x0[64], x1[64];
#pragma unroll
    for (int c4 = 0; c4 < 64; c4 += 4) {
      float4 v = *(const float4*)(pr + c4);
      x0[c4] = v.x; x0[c4 + 1] = v.y; x0[c4 + 2] = v.z; x0[c4 + 3] = v.w;
      float4 w = *(const float4*)(pr + 64 + c4);
      x1[c4] = w.x; x1[c4 + 1] = w.y; x1[c4 + 2] = w.z; x1[c4 + 3] = w.w;
    }
    row_triu_solve(x0, D0, rd0);
    row_dense_sub(x1, x0, D1);
    row_triu_solve(x1, D2, rd2);
#pragma unroll
    for (int c4 = 0; c4 < 64; c4 += 4) {
      float4 v = {x0[c4], x0[c4 + 1], x0[c4 + 2], x0[c4 + 3]};
      *(float4*)(pr + c4) = v;
      float4 w = {x1[c4], x1[c4 + 1], x1[c4 + 2], x1[c4 + 3]};
      *(float4*)(pr + 64 + c4) = w;
    }
  } else {
    const int col = k + 128 + ((int)blockIdx.x - nbrow) * 256 + t;
    if (col >= NDIM) return;
    float y0[64], y1[64];
#pragma unroll
    for (int j = 0; j < 64; ++j) {
      y0[j] = E[(size_t)(k + j) * NDIM + col];
      y1[j] = E[(size_t)(k + 64 + j) * NDIM + col];
    }
    col_unitL_solve(y0, D0);
    col_dense_sub(y1, y0, D1);
    col_unitL_solve(y1, D2);
#pragma unroll
    for (int j = 0; j < 64; ++j) {
      E[(size_t)(k + j) * NDIM + col] = y0[j];
      E[(size_t)(k + 64 + j) * NDIM + col] = y1[j];
    }
  }
}

// trailing update E22 -= L21*U12 (K=128), 128x128 tile, 512 threads.
// block (0,0) then LU-factors its (diagonal) tile in LDS.
__global__ __launch_bounds__(512) void lu_update128(float* __restrict__ E, int k) {
  __shared__ float sh[128 * 129];  // aliases: staging (6144 fl) then 128x129 tile
  float* As = sh;                  // [2][16][128]
  float* Bs = sh + 4096;
  const int t = threadIdx.x;
  const int tx = t & 31, ty = t >> 5;
  const int lr = t >> 2, lk = (t & 3) * 4;
  const int i0 = k + 128 + blockIdx.y * 128;
  const int j0 = k + 128 + blockIdx.x * 128;
  const float* Ap = E + (size_t)(i0 + lr) * NDIM + k + lk;
  const float* Bp = E + (size_t)(k + ty) * NDIM + j0 + tx * 4;
  float acc[8][4];
#pragma unroll
  for (int r = 0; r < 8; ++r)
#pragma unroll
    for (int c = 0; c < 4; ++c) acc[r][c] = 0.f;
  {
    float4 a = *(const float4*)Ap;
    float4 b = *(const float4*)Bp;
    As[(lk + 0) * 128 + lr] = a.x; As[(lk + 1) * 128 + lr] = a.y;
    As[(lk + 2) * 128 + lr] = a.z; As[(lk + 3) * 128 + lr] = a.w;
    *(float4*)&Bs[ty * 128 + tx * 4] = b;
  }
  int cur = 0;
  for (int k0 = 16;; k0 += 16) {
    const bool more = k0 < 128;
    float4 na, nb;
    if (more) {
      na = *(const float4*)(Ap + k0);
      nb = *(const float4*)(Bp + (size_t)k0 * NDIM);
    }
    __syncthreads();
#pragma unroll
    for (int kk = 0; kk < 16; ++kk) {
      float ra[8], rb[4];
#pragma unroll
      for (int r = 0; r < 8; ++r) ra[r] = As[cur * 2048 + kk * 128 + ty * 8 + r];
#pragma unroll
      for (int c = 0; c < 4; ++c) rb[c] = Bs[cur * 2048 + kk * 128 + tx * 4 + c];
#pragma unroll
      for (int r = 0; r < 8; ++r)
#pragma unroll
        for (int c = 0; c < 4; ++c) acc[r][c] += ra[r] * rb[c];
    }
    if (!more) break;
    const int nx = cur ^ 1;
    As[nx * 2048 + (lk + 0) * 128 + lr] = na.x; As[nx * 2048 + (lk + 1) * 128 + lr] = na.y;
    As[nx * 2048 + (lk + 2) * 128 + lr] = na.z; As[nx * 2048 + (lk + 3) * 128 + lr] = na.w;
    *(float4*)&Bs[nx * 2048 + ty * 128 + tx * 4] = nb;
    cur = nx;
  }
  if (!(blockIdx.x == 0 && blockIdx.y == 0)) {
#pragma unroll
    for (int r = 0; r < 8; ++r) {
      float* p = E + (size_t)(i0 + ty * 8 + r) * NDIM + j0 + tx * 4;
      float4 o = *(const float4*)p;
      float4 v = {o.x - acc[r][0], o.y - acc[r][1], o.z - acc[r][2], o.w - acc[r][3]};
      *(float4*)p = v;
    }
  } else {
    __syncthreads();  // staging dead; reuse sh as 128x129 tile
#pragma unroll
    for (int r = 0; r < 8; ++r) {
      const float* p = E + (size_t)(i0 + ty * 8 + r) * NDIM + j0 + tx * 4;
      float4 o = *(const float4*)p;
      sh[(ty * 8 + r) * 129 + tx * 4 + 0] = o.x - acc[r][0];
      sh[(ty * 8 + r) * 129 + tx * 4 + 1] = o.y - acc[r][1];
      sh[(ty * 8 + r) * 129 + tx * 4 + 2] = o.z - acc[r][2];
      sh[(ty * 8 + r) * 129 + tx * 4 + 3] = o.w - acc[r][3];
    }
    __syncthreads();
    lu128_inlds(sh, t);
    for (int idx = t; idx < 16384; idx += 512)
      E[(size_t)(i0 + (idx >> 7)) * NDIM + j0 + (idx & 127)] = sh[(idx >> 7) * 129 + (idx & 127)];
  }
}

// ==================== triangular solves on F (2048 RHS), NB=128 ===========
__global__ __launch_bounds__(256) void trsm_fwd128(const float* __restrict__ E,
                                                   float* __restrict__ F, int k) {
  __shared__ float D0[64 * 65], D1[64 * 65], D2[64 * 65];
  const int t = threadIdx.x;
  load64(D0, E + (size_t)k * NDIM + k, t, 256);
  load64(D1, E + (size_t)(k + 64) * NDIM + k, t, 256);
  load64(D2, E + (size_t)(k + 64) * NDIM + k + 64, t, 256);
  __syncthreads();
  const int col = (int)blockIdx.x * 256 + t;
  float y0[64], y1[64];
#pragma unroll
  for (int j = 0; j < 64; ++j) {
    y0[j] = F[(size_t)(k + j) * NDIM + col];
    y1[j] = F[(size_t)(k + 64 + j) * NDIM + col];
  }
  col_unitL_solve(y0, D0);
  col_dense_sub(y1, y0, D1);
  col_unitL_solve(y1, D2);
#pragma unroll
  for (int j = 0; j < 64; ++j) {
    F[(size_t)(k + j) * NDIM + col] = y0[j];
    F[(size_t)(k + 64 + j) * NDIM + col] = y1[j];
  }
}

__global__ __launch_bounds__(256) void trsm_bwd128(const float* __restrict__ E,
                                                   float* __restrict__ F, int d) {
  __shared__ float D0[64 * 65], D1[64 * 65], D2[64 * 65];
  __shared__ float rd0[64], rd2[64];
  const int t = threadIdx.x;
  load64(D0, E + (size_t)d * NDIM + d, t, 256);
  load64(D1, E + (size_t)d * NDIM + d + 64, t, 256);          // U01
  load64(D2, E + (size_t)(d + 64) * NDIM + d + 64, t, 256);   // U11
  __syncthreads();
  if (t < 64) { rd0[t] = 1.0f / D0[t * 65 + t]; rd2[t] = 1.0f / D2[t * 65 + t]; }
  __syncthreads();
  const int col = (int)blockIdx.x * 256 + t;
  float y0[64], y1[64];
#pragma unroll
  for (int j = 0; j < 64; ++j) {
    y0[j] = F[(size_t)(d + j) * NDIM + col];
    y1[j] = F[(size_t)(d + 64 + j) * NDIM + col];
  }
  col_triu_bwd_solve(y1, D2, rd2);
  col_dense_sub(y0, y1, D1);
  col_triu_bwd_solve(y0, D0, rd0);
#pragma unroll
  for (int j = 0; j < 64; ++j) {
    F[(size_t)(d + j) * NDIM + col] = y0[j];
    F[(size_t)(d + 64 + j) * NDIM + col] = y1[j];
  }
}

// fwd sweep: tiles (128 rows x 64 cols) of F below row k+128 get -= L*Y_k
// (K=128); blocks with by==0 then forward-solve their 128 rows.
__global__ __launch_bounds__(256) void fwd_update128(const float* __restrict__ E,
                                                     float* __restrict__ F, int k) {
  __shared__ float sh[20928];  // S[128*65]=8320 | D0,D1,D2 (3*4160) | rd 128
  float* As = sh;              // [2][16][128] = 4096 (aliased, dead before S)
  float* Bs = sh + 4096;       // [2][16][64] = 2048
  const int t = threadIdx.x;
  const int tx = t & 15, ty = t >> 4;
  const int i0 = k + 128 + (int)blockIdx.y * 128;
  const int j0 = (int)blockIdx.x * 64;
  const int lrA = t >> 1, lkA = (t & 1) * 8;
  const float* Ap = E + (size_t)(i0 + lrA) * NDIM + k + lkA;
  const float* Bp = F + (size_t)(k + ty) * NDIM + j0 + tx * 4;
  float acc[8][4];
#pragma unroll
  for (int r = 0; r < 8; ++r)
#pragma unroll
    for (int c = 0; c < 4; ++c) acc[r][c] = 0.f;
  {
    float4 a0 = *(const float4*)Ap, a1 = *(const float4*)(Ap + 4);
    float4 b = *(const float4*)Bp;
    As[(lkA + 0) * 128 + lrA] = a0.x; As[(lkA + 1) * 128 + lrA] = a0.y;
    As[(lkA + 2) * 128 + lrA] = a0.z; As[(lkA + 3) * 128 + lrA] = a0.w;
    As[(lkA + 4) * 128 + lrA] = a1.x; As[(lkA + 5) * 128 + lrA] = a1.y;
    As[(lkA + 6) * 128 + lrA] = a1.z; As[(lkA + 7) * 128 + lrA] = a1.w;
    *(float4*)&Bs[ty * 64 + tx * 4] = b;
  }
  int cur = 0;
  for (int k0 = 16;; k0 += 16) {
    const bool more = k0 < 128;
    float4 na0, na1, nb;
    if (more) {
      na0 = *(const float4*)(Ap + k0); na1 = *(const float4*)(Ap + k0 + 4);
      nb = *(const float4*)(Bp + (size_t)k0 * NDIM);
    }
    __syncthreads();
#pragma unroll
    for (int kk = 0; kk < 16; ++kk) {
      float ra[8], rb[4];
#pragma unroll
      for (int r = 0; r < 8; ++r) ra[r] = As[cur * 2048 + kk * 128 + ty * 8 + r];
#pragma unroll
      for (int c = 0; c < 4; ++c) rb[c] = Bs[cur * 1024 + kk * 64 + tx * 4 + c];
#pragma unroll
      for (int r = 0; r < 8; ++r)
#pragma unroll
        for (int c = 0; c < 4; ++c) acc[r][c] += ra[r] * rb[c];
    }
    if (!more) break;
    const int nx = cur ^ 1;
    As[nx * 2048 + (lkA + 0) * 128 + lrA] = na0.x; As[nx * 2048 + (lkA + 1) * 128 + lrA] = na0.y;
    As[nx * 2048 + (lkA + 2) * 128 + lrA] = na0.z; As[nx * 2048 + (lkA + 3) * 128 + lrA] = na0.w;
    As[nx * 2048 + (lkA + 4) * 128 + lrA] = na1.x; As[nx * 2048 + (lkA + 5) * 128 + lrA] = na1.y;
    As[nx * 2048 + (lkA + 6) * 128 + lrA] = na1.z; As[nx * 2048 + (lkA + 7) * 128 + lrA] = na1.w;
    *(float4*)&Bs[nx * 1024 + ty * 64 + tx * 4] = nb;
    cur = nx;
  }
  if (blockIdx.y != 0) {
#pragma unroll
    for (int r = 0; r < 8; ++r) {
      float* p = F + (size_t)(i0 + ty * 8 + r) * NDIM + j0 + tx * 4;
      float4 o = *(const float4*)p;
      float4 v = {o.x - acc[r][0], o.y - acc[r][1], o.z - acc[r][2], o.w - acc[r][3]};
      *(float4*)p = v;
    }
  } else {
    float* S = sh;            // 128 x 65
    float* D0 = sh + 8320;
    float* D1 = sh + 8320 + 4160;
    float* D2 = sh + 8320 + 8320;
    __syncthreads();          // staging reads done
#pragma unroll
    for (int r = 0; r < 8; ++r) {
      const float* p = F + (size_t)(i0 + ty * 8 + r) * NDIM + j0 + tx * 4;
      float4 o = *(const float4*)p;
      S[(ty * 8 + r) * 65 + tx * 4 + 0] = o.x - acc[r][0];
      S[(ty * 8 + r) * 65 + tx * 4 + 1] = o.y - acc[r][1];
      S[(ty * 8 + r) * 65 + tx * 4 + 2] = o.z - acc[r][2];
      S[(ty * 8 + r) * 65 + tx * 4 + 3] = o.w - acc[r][3];
    }
    load64(D0, E + (size_t)i0 * NDIM + i0, t, 256);
    load64(D1, E + (size_t)(i0 + 64) * NDIM + i0, t, 256);
    load64(D2, E + (size_t)(i0 + 64) * NDIM + i0 + 64, t, 256);
    __syncthreads();
    if (t < 64) {
      float y0[64], y1[64];
#pragma unroll
      for (int j = 0; j < 64; ++j) { y0[j] = S[j * 65 + t]; y1[j] = S[(64 + j) * 65 + t]; }
      col_unitL_solve(y0, D0);
      col_dense_sub(y1, y0, D1);
      col_unitL_solve(y1, D2);
#pragma unroll
      for (int j = 0; j < 64; ++j) {
        F[(size_t)(i0 + j) * NDIM + j0 + t] = y0[j];
        F[(size_t)(i0 + 64 + j) * NDIM + j0 + t] = y1[j];
      }
    }
  }
}

// bwd sweep: tiles (128 rows x 64 cols) of F above row k get -= U*X_k (K=128);
// blocks with by == k/128-1 then back-solve their 128 rows (diag at k-128).
__global__ __launch_bounds__(256) void bwd_update128(const float* __restrict__ E,
                                                     float* __restrict__ F, int k) {
  __shared__ float sh[20928];
  float* As = sh;
  float* Bs = sh + 4096;
  const int t = threadIdx.x;
  const int tx = t & 15, ty = t >> 4;
  const int i0 = (int)blockIdx.y * 128;
  const int j0 = (int)blockIdx.x * 64;
  const int lrA = t >> 1, lkA = (t & 1) * 8;
  const float* Ap = E + (size_t)(i0 + lrA) * NDIM + k + lkA;
  const float* Bp = F + (size_t)(k + ty) * NDIM + j0 + tx * 4;
  float acc[8][4];
#pragma unroll
  for (int r = 0; r < 8; ++r)
#pragma unroll
    for (int c = 0; c < 4; ++c) acc[r][c] = 0.f;
  {
    float4 a0 = *(const float4*)Ap, a1 = *(const float4*)(Ap + 4);
    float4 b = *(const float4*)Bp;
    As[(lkA + 0) * 128 + lrA] = a0.x; As[(lkA + 1) * 128 + lrA] = a0.y;
    As[(lkA + 2) * 128 + lrA] = a0.z; As[(lkA + 3) * 128 + lrA] = a0.w;
    As[(lkA + 4) * 128 + lrA] = a1.x; As[(lkA + 5) * 128 + lrA] = a1.y;
    As[(lkA + 6) * 128 + lrA] = a1.z; As[(lkA + 7) * 128 + lrA] = a1.w;
    *(float4*)&Bs[ty * 64 + tx * 4] = b;
  }
  int cur = 0;
  for (int k0 = 16;; k0 += 16) {
    const bool more = k0 < 128;
    float4 na0, na1, nb;
    if (more) {
      na0 = *(const float4*)(Ap + k0); na1 = *(const float4*)(Ap + k0 + 4);
      nb = *(const float4*)(Bp + (size_t)k0 * NDIM);
    }
    __syncthreads();
#pragma unroll
    for (int kk = 0; kk < 16; ++kk) {
      float ra[8], rb[4];
#pragma unroll
      for (int r = 0; r < 8; ++r) ra[r] = As[cur * 2048 + kk * 128 + ty * 8 + r];
#pragma unroll
      for (int c = 0; c < 4; ++c) rb[c] = Bs[cur * 1024 + kk * 64 + tx * 4 + c];
#pragma unroll
      for (int r = 0; r < 8; ++r)
#pragma unroll
        for (int c = 0; c < 4; ++c) acc[r][c] += ra[r] * rb[c];
    }
    if (!more) break;
    const int nx = cur ^ 1;
    As[nx * 2048 + (lkA + 0) * 128 + lrA] = na0.x; As[nx * 2048 + (lkA + 1) * 128 + lrA] = na0.y;
    As[nx * 2048 + (lkA + 2) * 128 + lrA] = na0.z; As[nx * 2048 + (lkA + 3) * 128 + lrA] = na0.w;
    As[nx * 2048 + (lkA + 4) * 128 + lrA] = na1.x; As[nx * 2048 + (lkA + 5) * 128 + lrA] = na1.y;
    As[nx * 2048 + (lkA + 6) * 128 + lrA] = na1.z; As[nx * 2048 + (lkA + 7) * 128 + lrA] = na1.w;
    *(float4*)&Bs[nx * 1024 + ty * 64 + tx * 4] = nb;
    cur = nx;
  }
  if ((int)blockIdx.y != (k >> 7) - 1) {
#pragma unroll
    for (int r = 0; r < 8; ++r) {
      float* p = F + (size_t)(i0 + ty * 8 + r) * NDIM + j0 + tx * 4;
      float4 o = *(const float4*)p;
      float4 v = {o.x - acc[r][0], o.y - acc[r][1], o.z - acc[r][2], o.w - acc[r][3]};
      *(float4*)p = v;
    }
  } else {
    float* S = sh;
    float* D0 = sh + 8320;
    float* D1 = sh + 8320 + 4160;
    float* D2 = sh + 8320 + 8320;
    float* rdx = sh + 8320 + 12480;  // rd0 | rd2
    __syncthreads();
#pragma unroll
    for (int r = 0; r < 8; ++r) {
      const float* p = F + (size_t)(i0 + ty * 8 + r) * NDIM + j0 + tx * 4;
      float4 o = *(const float4*)p;
      S[(ty * 8 + r) * 65 + tx * 4 + 0] = o.x - acc[r][0];
      S[(ty * 8 + r) * 65 + tx * 4 + 1] = o.y - acc[r][1];
      S[(ty * 8 + r) * 65 + tx * 4 + 2] = o.z - acc[r][2];
      S[(ty * 8 + r) * 65 + tx * 4 + 3] = o.w - acc[r][3];
    }
    load64(D0, E + (size_t)i0 * NDIM + i0, t, 256);
    load64(D1, E + (size_t)i0 * NDIM + i0 + 64, t, 256);
    load64(D2, E + (size_t)(i0 + 64) * NDIM + i0 + 64, t, 256);
    __syncthreads();
    if (t < 64) { rdx[t] = 1.0f / D0[t * 65 + t]; rdx[64 + t] = 1.0f / D2[t * 65 + t]; }
    __syncthreads();
    if (t < 64) {
      float y0[64], y1[64];
#pragma unroll
      for (int j = 0; j < 64; ++j) { y0[j] = S[j * 65 + t]; y1[j] = S[(64 + j) * 65 + t]; }
      col_triu_bwd_solve(y1, D2, rdx + 64);
      col_dense_sub(y0, y1, D1);
      col_triu_bwd_solve(y0, D0, rdx);
#pragma unroll
      for (int j = 0; j < 64; ++j) {
        F[(size_t)(i0 + j) * NDIM + j0 + t] = y0[j];
        F[(size_t)(i0 + 64 + j) * NDIM + j0 + t] = y1[j];
      }
    }
  }
}

extern "C" void kernel_launch(void* const* d_in, const int* in_sizes, int n_in,
                              void* d_out, int out_size, void* d_ws, size_t ws_size,
                              hipStream_t stream) {
  const float* L = (const float*)d_in[0];
  const float* R = (const float*)d_in[1];
  const float* Bin = (const float*)d_in[2];

  float* ws = (float*)d_ws;
  float* P = ws;                       // 2048^2
  float* F = ws + (size_t)NN;          // 2048^2: F -> Y -> Acl -> A
  float* C1 = ws + (size_t)2 * NN;     // 256 x 2048
  float* W = C1 + (size_t)256 * NDIM;  // 256 x 2048
  float* E = (float*)d_out;            // LU factors live in d_out until the end

  const float* L1 = L;
  const float* L2 = L + (size_t)NDIM * KDIM;

  dim3 g16(16, 16);
  gemm_nt_big<<<g16, 512, 0, stream>>>(L2, L2, P);
  gemm_nt_big<<<g16, 512, 0, stream>>>(L2, L1, F);
  gemm_nt_big<<<g16, 512, 0, stream>>>(L1, L1, E);
  make_E<<<dim3(32, 32), 256, 0, stream>>>(E, P, R);

  // ---- LU (no pivoting), NB = 128; diag LU fused into trailing update
  lu_diag128<<<1, 512, 0, stream>>>(E, 0);
  for (int k = 0; k + 128 < NDIM; k += 128) {
    const int rem = NDIM - k - 128;
    const int nb = (rem + 255) / 256;
    lu_panels128<<<2 * nb, 256, 0, stream>>>(E, k, nb);
    lu_update128<<<dim3(rem / 128, rem / 128), 512, 0, stream>>>(E, k);
  }

  // ---- forward solve L Y = F
  trsm_fwd128<<<8, 256, 0, stream>>>(E, F, 0);
  for (int k = 0; k + 128 < NDIM; k += 128)
    fwd_update128<<<dim3(32, (NDIM - k - 128) / 128), 256, 0, stream>>>(E, F, k);

  // ---- backward solve U X = Y
  trsm_bwd128<<<8, 256, 0, stream>>>(E, F, NDIM - 128);
  for (int k = NDIM - 128; k >= 128; k -= 128)
    bwd_update128<<<dim3(32, k / 128), 256, 0, stream>>>(E, F, k);

  // ---- A = (I - B (B^T P)) Acl
  gemm_tile64<true><<<dim3(32, 4), 256, 0, stream>>>(Bin, P, C1, 256, NDIM, NDIM,
                                                     256, NDIM, NDIM, 1.f, 0.f);
  gemm_tile64<false><<<dim3(32, 4), 256, 0, stream>>>(C1, F, W, 256, NDIM, NDIM,
                                                      NDIM, NDIM, NDIM, 1.f, 0.f);
  gemm_tile64<false><<<dim3(32, 32), 256, 0, stream>>>(Bin, W, F, NDIM, NDIM, 256,
                                                       256, NDIM, NDIM, -1.f, 1.f);
  hipMemcpyAsync(d_out, F, (size_t)NN * sizeof(float), hipMemcpyDeviceToDevice,
                 stream);
}